// Round 15
// baseline (1308.667 us; speedup 1.0000x reference)
//
#include <hip/hip_runtime.h>
#include <hip/hip_bf16.h>

#define N_NODES 8192
#define N_EDGES 524288
#define TOT_EDGES (N_EDGES + N_NODES)   /* 532480 */
#define IN_DIM 256
#define HID1 128
#define HID2 64
#define DC 128      /* combined [mu | lv] feature dim */
#define CAP 192     /* slot capacity per row; max expected degree ~105 */
#define FILL_BLK 520
#define REP 24      /* attribution repeat factor (small kernels only) */

typedef __attribute__((ext_vector_type(8))) short bf16x8;
typedef __attribute__((ext_vector_type(4))) float f32x4;
typedef __attribute__((ext_vector_type(4))) int   i32x4;
typedef __attribute__((ext_vector_type(4))) unsigned short u16x4;

__device__ __forceinline__ float b2f(unsigned short u){
    unsigned int v = ((unsigned int)u) << 16;
    float f; __builtin_memcpy(&f, &v, 4); return f;
}
__device__ __forceinline__ unsigned short f2b(float f){
    __hip_bfloat16 h = __float2bfloat16(f);
    return *(unsigned short*)&h;
}
__device__ __forceinline__ size_t lz(){            // laundered zero (defeats cross-iteration CSE)
    size_t z = 0; asm volatile("" : "+v"(z)); return z;
}

// ---------------- D1: zero fillc+fillS (blocks 0..15) + wcomb (blocks 16..143)  [x REP] ----------------

__global__ __launch_bounds__(256) void k_pre(const float* __restrict__ W1, const float* __restrict__ W2,
                                             const float* __restrict__ Wmu, const float* __restrict__ Wlv,
                                             const float* __restrict__ b1, const float* __restrict__ b2,
                                             unsigned short* __restrict__ WcT, float* __restrict__ cvec,
                                             float* __restrict__ zbase){
    int b = blockIdx.x, t = threadIdx.x;
    for (int it=0; it<REP; ++it){
        if (b < 16){
            ((f32x4*)(zbase + lz()))[b*256 + t] = (f32x4){0.f,0.f,0.f,0.f};
        } else {
            const float* W1p = W1 + lz();
            int r = (b - 16)*2 + (t >> 7);      // 0..255
            int j = t & 127;                    // wave-uniform Wsel select
            const float* Wsel = (j < 64) ? Wmu : Wlv;
            int jj = j & 63;
            float acc = 0.f;
            for (int k=0;k<HID1;k++){
                acc += W1p[r*HID1+k] * Wsel[k*HID2+jj] + W2[r*HID1+k] * Wsel[(HID1+k)*HID2+jj];
            }
            WcT[(size_t)j*IN_DIM + r] = f2b(acc);
            if (r == 0){
                float c = 0.f;
                for (int k=0;k<HID1;k++){
                    c += b1[k]*Wsel[k*HID2+jj] + b2[k]*Wsel[(HID1+k)*HID2+jj];
                }
                cvec[j] = c;
            }
        }
    }
}

// ---------------- D2: slot fill (blocks 0..519) + gemm_u (blocks 520..775)  [x REP] ----------------

__global__ __launch_bounds__(256) void k_fill_gemm(const int* __restrict__ ei, int* __restrict__ fillc,
                                                   unsigned short* __restrict__ slots,
                                                   const float* __restrict__ x,
                                                   const unsigned short* __restrict__ WcT,
                                                   unsigned short* __restrict__ Ubf,
                                                   int* __restrict__ fillS, unsigned short* __restrict__ slotsS){
    int b = blockIdx.x, t = threadIdx.x;
    if (b < FILL_BLK){
        int e4 = (b*256 + t)*4;
        if (e4 >= TOT_EDGES) return;
        if (e4 < N_EDGES){
            i32x4 rr = *(const i32x4*)(ei + e4);
            i32x4 cc = *(const i32x4*)(ei + N_EDGES + e4);
            for (int it=0; it<REP; ++it){
                int* f = (it == 0) ? fillc : fillS;
                unsigned short* sl = (it == 0) ? slots : slotsS;
                #pragma unroll
                for (int j=0;j<4;j++){
                    int s = atomicAdd(&f[rr[j]], 1);
                    if (it > 0) s = s % CAP;
                    if (s < CAP) sl[(size_t)rr[j]*CAP + s] = (unsigned short)cc[j];
                }
            }
        } else {
            for (int it=0; it<REP; ++it){
                int* f = (it == 0) ? fillc : fillS;
                unsigned short* sl = (it == 0) ? slots : slotsS;
                #pragma unroll
                for (int j=0;j<4;j++){
                    int r = e4 - N_EDGES + j;
                    int s = atomicAdd(&f[r], 1);
                    if (it > 0) s = s % CAP;
                    if (s < CAP) sl[(size_t)r*CAP + s] = (unsigned short)r;
                }
            }
        }
    } else {
        // U = x @ Wc via bf16 MFMA; A-fragments converted f32->bf16 in-register.
        int l  = t & 63;
        int w  = t >> 6;
        int Ibase = (b - FILL_BLK)*32;
        int Jbase = w*32;
        int lr = l & 15;
        int kg = l >> 4;
        for (int it=0; it<REP; ++it){
            const float* xp = x + lz();
            f32x4 acc[2][2];
            #pragma unroll
            for (int mt=0;mt<2;mt++)
                #pragma unroll
                for (int nt=0;nt<2;nt++) acc[mt][nt] = (f32x4){0.f,0.f,0.f,0.f};
            #pragma unroll
            for (int kc=0; kc<IN_DIM/32; kc++){
                bf16x8 a[2], bb[2];
                #pragma unroll
                for (int mt=0;mt<2;mt++){
                    const float* xr = xp + (size_t)(Ibase+mt*16+lr)*IN_DIM + kc*32 + kg*8;
                    f32x4 v0 = *(const f32x4*)xr;
                    f32x4 v1 = *(const f32x4*)(xr + 4);
                    #pragma unroll
                    for (int j=0;j<4;j++){
                        a[mt][j]   = (short)f2b(v0[j]);
                        a[mt][4+j] = (short)f2b(v1[j]);
                    }
                }
                #pragma unroll
                for (int nt=0;nt<2;nt++)
                    bb[nt] = *(const bf16x8*)(WcT + (size_t)(Jbase+nt*16+lr)*IN_DIM + kc*32 + kg*8);
                #pragma unroll
                for (int mt=0;mt<2;mt++)
                    #pragma unroll
                    for (int nt=0;nt<2;nt++)
                        acc[mt][nt] = __builtin_amdgcn_mfma_f32_16x16x32_bf16(a[mt], bb[nt], acc[mt][nt], 0, 0, 0);
            }
            #pragma unroll
            for (int mt=0;mt<2;mt++)
                #pragma unroll
                for (int r=0;r<4;r++){
                    int grow = Ibase + mt*16 + kg*4 + r;
                    #pragma unroll
                    for (int nt=0;nt<2;nt++)
                        Ubf[(size_t)grow*DC + Jbase + nt*16 + lr] = f2b(acc[mt][nt][r]);
                }
        }
    }
}

// ---------------- D3: SpMM Tbf = A_hat * Ubf  (wave-per-row, barrier-free)  [x REP] ----------------

__global__ __launch_bounds__(256) void k_spmm(const unsigned short* __restrict__ IN,
                                              const unsigned short* __restrict__ slots,
                                              const int* __restrict__ fillc,
                                              unsigned short* __restrict__ OUT){
    int tid = threadIdx.x;
    int i = blockIdx.x*4 + (tid >> 6);     // row (one per wave)
    int l  = tid & 15;                     // dim-lane
    int eg = (tid >> 4) & 3;               // edge-group
    int deg = min(fillc[i], CAP);
    const unsigned short* sl = slots + (size_t)i*CAP;
    for (int it=0; it<REP; ++it){
        const unsigned short* INp = IN + lz();
        float acc[8] = {0.f,0.f,0.f,0.f,0.f,0.f,0.f,0.f};
        for (int e = eg; e < deg; e += 4){
            int c = sl[e];
            float wgt = rsqrtf((float)fillc[c]);   // deg >= 1 always (self-loop)
            bf16x8 v = *(const bf16x8*)(INp + (size_t)c*DC + l*8);
            #pragma unroll
            for (int j=0;j<8;j++) acc[j] += wgt * b2f((unsigned short)v[j]);
        }
        #pragma unroll
        for (int j=0;j<8;j++){
            acc[j] += __shfl_xor(acc[j], 16);
            acc[j] += __shfl_xor(acc[j], 32);
        }
        if (eg == 0){
            float di = rsqrtf((float)fillc[i]);
            bf16x8 o;
            #pragma unroll
            for (int j=0;j<8;j++) o[j] = (short)f2b(di*acc[j]);
            *(bf16x8*)(OUT + (size_t)i*DC + l*8) = o;
        }
    }
}

// ---------------- D4: second SpMM + rank-1 bias + outputs (barrier-free)  [x REP] ----------------

__global__ __launch_bounds__(256) void k_spmm_out(const unsigned short* __restrict__ T,
                                                  const unsigned short* __restrict__ slots,
                                                  const int* __restrict__ fillc,
                                                  const float* __restrict__ cvec,
                                                  const float* __restrict__ bmu, const float* __restrict__ blv,
                                                  float* __restrict__ outMu, float* __restrict__ outLv,
                                                  unsigned short* __restrict__ muBf){
    int tid = threadIdx.x;
    int i = blockIdx.x*4 + (tid >> 6);
    int l  = tid & 15;
    int eg = (tid >> 4) & 3;
    int deg = min(fillc[i], CAP);
    const unsigned short* sl = slots + (size_t)i*CAP;
    for (int it=0; it<REP; ++it){
        const unsigned short* Tp = T + lz();
        float acc[8] = {0.f,0.f,0.f,0.f,0.f,0.f,0.f,0.f};
        float wsum = 0.f;
        for (int e = eg; e < deg; e += 4){
            int c = sl[e];
            float wgt = rsqrtf((float)fillc[c]);
            wsum += wgt;
            bf16x8 v = *(const bf16x8*)(Tp + (size_t)c*DC + l*8);
            #pragma unroll
            for (int j=0;j<8;j++) acc[j] += wgt * b2f((unsigned short)v[j]);
        }
        #pragma unroll
        for (int j=0;j<8;j++){
            acc[j] += __shfl_xor(acc[j], 16);
            acc[j] += __shfl_xor(acc[j], 32);
        }
        wsum += __shfl_xor(wsum, 16);
        wsum += __shfl_xor(wsum, 32);
        if (eg == 0){
            float di = rsqrtf((float)fillc[i]);
            float sv = di * wsum;                       // (A_hat . 1)_i
            float val[8];
            #pragma unroll
            for (int j=0;j<8;j++) val[j] = di*acc[j] + sv*cvec[l*8+j];
            if (l < 8){
                f32x4 v0, v1; bf16x8 o;
                #pragma unroll
                for (int j=0;j<8;j++){
                    float vv = val[j] + bmu[l*8+j];
                    if (j<4) v0[j] = vv; else v1[j-4] = vv;
                    o[j] = (short)f2b(vv);
                }
                *(f32x4*)(outMu + (size_t)i*HID2 + l*8)     = v0;
                *(f32x4*)(outMu + (size_t)i*HID2 + l*8 + 4) = v1;
                *(bf16x8*)(muBf + (size_t)i*HID2 + l*8)     = o;
            } else {
                int d = (l-8)*8;
                f32x4 v0, v1;
                #pragma unroll
                for (int j=0;j<8;j++){
                    float vv = val[j] + blv[d+j];
                    if (j<4) v0[j] = vv; else v1[j-4] = vv;
                }
                *(f32x4*)(outLv + (size_t)i*HID2 + d)     = v0;
                *(f32x4*)(outLv + (size_t)i*HID2 + d + 4) = v1;
            }
        }
    }
}

// ---------------- D5: adj = sigmoid(mu @ mu^T) — R14 structure (x1, unchanged) ----------------

__global__ __launch_bounds__(256) void k_adj(const unsigned short* __restrict__ mu, float* __restrict__ adj){
    int t  = threadIdx.x;
    int l  = t & 63;
    int w  = t >> 6;
    int wr = w >> 1, wc = w & 1;
    int Ibase = blockIdx.y*128 + wr*64;
    int Jbase = blockIdx.x*128 + wc*64;
    int lr = l & 15;
    int kg = l >> 4;

    bf16x8 afr[4][2], bfr[4][2];
    #pragma unroll
    for (int mt=0; mt<4; mt++){
        const unsigned short* p = mu + (size_t)(Ibase + mt*16 + lr)*HID2 + kg*8;
        afr[mt][0] = *(const bf16x8*)(p);
        afr[mt][1] = *(const bf16x8*)(p + 32);
    }
    #pragma unroll
    for (int nt=0; nt<4; nt++){
        const unsigned short* p = mu + (size_t)(Jbase + nt*16 + lr)*HID2 + kg*8;
        bfr[nt][0] = *(const bf16x8*)(p);
        bfr[nt][1] = *(const bf16x8*)(p + 32);
    }

    f32x4 acc[4][4];
    #pragma unroll
    for (int mt=0; mt<4; mt++)
        #pragma unroll
        for (int nt=0; nt<4; nt++)
            acc[mt][nt] = (f32x4){0.f,0.f,0.f,0.f};

    #pragma unroll
    for (int kc=0; kc<2; kc++)
        #pragma unroll
        for (int mt=0; mt<4; mt++)
            #pragma unroll
            for (int nt=0; nt<4; nt++)
                acc[mt][nt] = __builtin_amdgcn_mfma_f32_16x16x32_bf16(afr[mt][kc], bfr[nt][kc], acc[mt][nt], 0, 0, 0);

    __shared__ float wt[4][16][68];
    float* myt = &wt[w][0][0];
    #pragma unroll
    for (int mt=0; mt<4; mt++){
        asm volatile("s_waitcnt lgkmcnt(0)" ::: "memory");
        #pragma unroll
        for (int nt=0; nt<4; nt++)
            #pragma unroll
            for (int r=0; r<4; r++)
                myt[(kg*4+r)*68 + nt*16 + lr] = acc[mt][nt][r];
        asm volatile("s_waitcnt lgkmcnt(0)" ::: "memory");
        __builtin_amdgcn_sched_barrier(0);
        #pragma unroll
        for (int p=0; p<4; p++){
            int row = p*4 + (l >> 4);          // 0..15
            int col = (l & 15)*4;              // 0..60
            f32x4 v = *(const f32x4*)&myt[row*68 + col];
            f32x4 o;
            #pragma unroll
            for (int j=0;j<4;j++)
                o[j] = __builtin_amdgcn_rcpf(1.f + __expf(-v[j]));
            __builtin_nontemporal_store(o, (f32x4*)(adj + (size_t)(Ibase + mt*16 + row)*N_NODES + Jbase + col));
        }
    }
}

// ---------------- launch ----------------

extern "C" void kernel_launch(void* const* d_in, const int* in_sizes, int n_in,
                              void* d_out, int out_size, void* d_ws, size_t ws_size,
                              hipStream_t stream){
    const float* x   = (const float*)d_in[0];
    const int*   ei  = (const int*)  d_in[1];
    const float* W1  = (const float*)d_in[2];
    const float* b1  = (const float*)d_in[3];
    const float* W2  = (const float*)d_in[4];
    const float* b2  = (const float*)d_in[5];
    const float* Wmu = (const float*)d_in[6];
    const float* bmu = (const float*)d_in[7];
    const float* Wlv = (const float*)d_in[8];
    const float* blv = (const float*)d_in[9];

    char* ws = (char*)d_ws;
    int*   fillc  = (int*)  (ws + 0);        // 32 KB (zeroed by k_pre)
    int*   fillS  = (int*)  (ws + 32768);    // 32 KB (zeroed by k_pre) — attribution scratch
    unsigned short* WcT = (unsigned short*)(ws + 65536);   // 64 KB -> 131072
    float* cvec   = (float*)(ws + 131072);   // 512 B -> 131584
    unsigned short* muBf = (unsigned short*)(ws + 131584); // 1 MB -> 1,180,160

    float* adj   = (float*)d_out;
    float* outMu = adj + (size_t)N_NODES*N_NODES;
    float* outLv = outMu + (size_t)N_NODES*HID2;

    // dead adj region reused as scratch (overwritten by k_adj at the end):
    unsigned short* Ubf    = (unsigned short*)adj;                          // [0, 2MB)
    unsigned short* Tbf    = (unsigned short*)((char*)adj + 16*1024*1024);  // [16MB, 18MB)
    unsigned short* slots  = (unsigned short*)((char*)adj + 32*1024*1024);  // [32MB, +3MB)
    unsigned short* slotsS = (unsigned short*)((char*)adj + 48*1024*1024);  // [48MB, +3MB) scratch

    k_pre      <<<144, 256, 0, stream>>>(W1, W2, Wmu, Wlv, b1, b2, WcT, cvec, (float*)ws);
    k_fill_gemm<<<FILL_BLK + 256, 256, 0, stream>>>(ei, fillc, slots, x, WcT, Ubf, fillS, slotsS);
    k_spmm     <<<N_NODES/4, 256, 0, stream>>>(Ubf, slots, fillc, Tbf);
    k_spmm_out <<<N_NODES/4, 256, 0, stream>>>(Tbf, slots, fillc, cvec, bmu, blv,
                                               outMu, outLv, muBf);
    k_adj      <<<dim3(N_NODES/128, N_NODES/128), 256, 0, stream>>>(muBf, adj);
}

// Round 16
// 126.241 us; speedup vs baseline: 10.3664x; 10.3664x over previous
//
#include <hip/hip_runtime.h>
#include <hip/hip_bf16.h>

#define N_NODES 8192
#define N_EDGES 524288
#define TOT_EDGES (N_EDGES + N_NODES)   /* 532480 */
#define IN_DIM 256
#define HID1 128
#define HID2 64
#define DC 128      /* combined [mu | lv] feature dim */
#define CAP 192     /* slot capacity per row; max expected degree ~105 */
#define FILL_BLK 520

typedef __attribute__((ext_vector_type(8))) short bf16x8;
typedef __attribute__((ext_vector_type(4))) float f32x4;
typedef __attribute__((ext_vector_type(4))) int   i32x4;
typedef __attribute__((ext_vector_type(4))) unsigned short u16x4;

__device__ __forceinline__ float b2f(unsigned short u){
    unsigned int v = ((unsigned int)u) << 16;
    float f; __builtin_memcpy(&f, &v, 4); return f;
}
__device__ __forceinline__ unsigned short f2b(float f){
    __hip_bfloat16 h = __float2bfloat16(f);
    return *(unsigned short*)&h;
}

// ---------------- D1: zero fillc (blocks 0..7) + wcomb (blocks 8..135) ----------------

__global__ __launch_bounds__(256) void k_pre(const float* __restrict__ W1, const float* __restrict__ W2,
                                             const float* __restrict__ Wmu, const float* __restrict__ Wlv,
                                             const float* __restrict__ b1, const float* __restrict__ b2,
                                             unsigned short* __restrict__ WcT, float* __restrict__ cvec,
                                             float* __restrict__ zbase){
    int b = blockIdx.x, t = threadIdx.x;
    if (b < 8){
        ((f32x4*)zbase)[b*256 + t] = (f32x4){0.f,0.f,0.f,0.f};
    } else {
        int r = (b - 8)*2 + (t >> 7);       // 0..255
        int j = t & 127;                    // wave-uniform Wsel select
        const float* Wsel = (j < 64) ? Wmu : Wlv;
        int jj = j & 63;
        float acc = 0.f;
        for (int k=0;k<HID1;k++){
            acc += W1[r*HID1+k] * Wsel[k*HID2+jj] + W2[r*HID1+k] * Wsel[(HID1+k)*HID2+jj];
        }
        WcT[(size_t)j*IN_DIM + r] = f2b(acc);
        if (r == 0){
            float c = 0.f;
            for (int k=0;k<HID1;k++){
                c += b1[k]*Wsel[k*HID2+jj] + b2[k]*Wsel[(HID1+k)*HID2+jj];
            }
            cvec[j] = c;
        }
    }
}

// ---------------- D2: slot fill (blocks 0..519, NT slot stores) + gemm_u (blocks 520..775) ----------------

__global__ __launch_bounds__(256) void k_fill_gemm(const int* __restrict__ ei, int* __restrict__ fillc,
                                                   unsigned short* __restrict__ slots,
                                                   const float* __restrict__ x,
                                                   const unsigned short* __restrict__ WcT,
                                                   unsigned short* __restrict__ Ubf){
    int b = blockIdx.x, t = threadIdx.x;
    if (b < FILL_BLK){
        int e4 = (b*256 + t)*4;
        if (e4 >= TOT_EDGES) return;
        if (e4 < N_EDGES){
            i32x4 rr = *(const i32x4*)(ei + e4);
            i32x4 cc = *(const i32x4*)(ei + N_EDGES + e4);
            #pragma unroll
            for (int j=0;j<4;j++){
                int s = atomicAdd(&fillc[rr[j]], 1);
                if (s < CAP) __builtin_nontemporal_store((unsigned short)cc[j],
                                 slots + (size_t)rr[j]*CAP + s);
            }
        } else {
            #pragma unroll
            for (int j=0;j<4;j++){
                int r = e4 - N_EDGES + j;
                int s = atomicAdd(&fillc[r], 1);
                if (s < CAP) __builtin_nontemporal_store((unsigned short)r,
                                 slots + (size_t)r*CAP + s);
            }
        }
    } else {
        // U = x @ Wc via bf16 MFMA; A-fragments converted f32->bf16 in-register.
        int l  = t & 63;
        int w  = t >> 6;
        int Ibase = (b - FILL_BLK)*32;
        int Jbase = w*32;
        int lr = l & 15;
        int kg = l >> 4;
        f32x4 acc[2][2];
        #pragma unroll
        for (int mt=0;mt<2;mt++)
            #pragma unroll
            for (int nt=0;nt<2;nt++) acc[mt][nt] = (f32x4){0.f,0.f,0.f,0.f};
        #pragma unroll
        for (int kc=0; kc<IN_DIM/32; kc++){
            bf16x8 a[2], bb[2];
            #pragma unroll
            for (int mt=0;mt<2;mt++){
                const float* xr = x + (size_t)(Ibase+mt*16+lr)*IN_DIM + kc*32 + kg*8;
                f32x4 v0 = *(const f32x4*)xr;
                f32x4 v1 = *(const f32x4*)(xr + 4);
                #pragma unroll
                for (int j=0;j<4;j++){
                    a[mt][j]   = (short)f2b(v0[j]);
                    a[mt][4+j] = (short)f2b(v1[j]);
                }
            }
            #pragma unroll
            for (int nt=0;nt<2;nt++)
                bb[nt] = *(const bf16x8*)(WcT + (size_t)(Jbase+nt*16+lr)*IN_DIM + kc*32 + kg*8);
            #pragma unroll
            for (int mt=0;mt<2;mt++)
                #pragma unroll
                for (int nt=0;nt<2;nt++)
                    acc[mt][nt] = __builtin_amdgcn_mfma_f32_16x16x32_bf16(a[mt], bb[nt], acc[mt][nt], 0, 0, 0);
        }
        #pragma unroll
        for (int mt=0;mt<2;mt++)
            #pragma unroll
            for (int r=0;r<4;r++){
                int grow = Ibase + mt*16 + kg*4 + r;
                #pragma unroll
                for (int nt=0;nt<2;nt++)
                    Ubf[(size_t)grow*DC + Jbase + nt*16 + lr] = f2b(acc[mt][nt][r]);
            }
    }
}

// ---------------- D3: SpMM  Td = dinv.(dinv.Sum(dinv_c U[c]) + cvec)  (pre-scaled for hop 2) ----------------

__global__ __launch_bounds__(256) void k_spmm(const unsigned short* __restrict__ IN,
                                              const unsigned short* __restrict__ slots,
                                              const int* __restrict__ fillc,
                                              const float* __restrict__ cvec,
                                              unsigned short* __restrict__ OUT){
    int tid = threadIdx.x;
    int i = blockIdx.x*4 + (tid >> 6);     // row (one per wave)
    int l  = tid & 15;                     // dim-lane
    int eg = (tid >> 4) & 3;               // edge-group
    int deg = min(fillc[i], CAP);
    const unsigned short* sl = slots + (size_t)i*CAP;
    float acc[8] = {0.f,0.f,0.f,0.f,0.f,0.f,0.f,0.f};
    #pragma unroll 2
    for (int e = eg; e < deg; e += 4){
        int c = sl[e];
        float wgt = rsqrtf((float)fillc[c]);   // deg >= 1 always (self-loop)
        bf16x8 v = *(const bf16x8*)(IN + (size_t)c*DC + l*8);
        #pragma unroll
        for (int j=0;j<8;j++) acc[j] += wgt * b2f((unsigned short)v[j]);
    }
    #pragma unroll
    for (int j=0;j<8;j++){
        acc[j] += __shfl_xor(acc[j], 16);
        acc[j] += __shfl_xor(acc[j], 32);
    }
    if (eg == 0){
        float di = rsqrtf((float)fillc[i]);
        bf16x8 o;
        #pragma unroll
        for (int j=0;j<8;j++){
            float tprime = di*acc[j] + cvec[l*8+j];    // hop-1 result + folded bias row
            o[j] = (short)f2b(di*tprime);              // pre-scale by dinv_i for hop 2
        }
        *(bf16x8*)(OUT + (size_t)i*DC + l*8) = o;
    }
}

// ---------------- D4: hop 2 — pure gather (no per-edge weights) + bias + outputs ----------------

__global__ __launch_bounds__(256) void k_spmm_out(const unsigned short* __restrict__ T,
                                                  const unsigned short* __restrict__ slots,
                                                  const int* __restrict__ fillc,
                                                  const float* __restrict__ bmu, const float* __restrict__ blv,
                                                  float* __restrict__ outMu, float* __restrict__ outLv,
                                                  unsigned short* __restrict__ muBf){
    int tid = threadIdx.x;
    int i = blockIdx.x*4 + (tid >> 6);
    int l  = tid & 15;
    int eg = (tid >> 4) & 3;
    int deg = min(fillc[i], CAP);
    const unsigned short* sl = slots + (size_t)i*CAP;
    float acc[8] = {0.f,0.f,0.f,0.f,0.f,0.f,0.f,0.f};
    #pragma unroll 2
    for (int e = eg; e < deg; e += 4){
        int c = sl[e];
        bf16x8 v = *(const bf16x8*)(T + (size_t)c*DC + l*8);
        #pragma unroll
        for (int j=0;j<8;j++) acc[j] += b2f((unsigned short)v[j]);
    }
    #pragma unroll
    for (int j=0;j<8;j++){
        acc[j] += __shfl_xor(acc[j], 16);
        acc[j] += __shfl_xor(acc[j], 32);
    }
    if (eg == 0){
        float di = rsqrtf((float)fillc[i]);
        if (l < 8){
            f32x4 v0, v1; bf16x8 o;
            #pragma unroll
            for (int j=0;j<8;j++){
                float vv = di*acc[j] + bmu[l*8+j];
                if (j<4) v0[j] = vv; else v1[j-4] = vv;
                o[j] = (short)f2b(vv);
            }
            *(f32x4*)(outMu + (size_t)i*HID2 + l*8)     = v0;
            *(f32x4*)(outMu + (size_t)i*HID2 + l*8 + 4) = v1;
            *(bf16x8*)(muBf + (size_t)i*HID2 + l*8)     = o;
        } else {
            int d = (l-8)*8;
            f32x4 v0, v1;
            #pragma unroll
            for (int j=0;j<8;j++){
                float vv = di*acc[j] + blv[d+j];
                if (j<4) v0[j] = vv; else v1[j-4] = vv;
            }
            *(f32x4*)(outLv + (size_t)i*HID2 + d)     = v0;
            *(f32x4*)(outLv + (size_t)i*HID2 + d + 4) = v1;
        }
    }
}

// ---------------- D5: adj = sigmoid(mu @ mu^T) — R14 structure (best measured) ----------------

__global__ __launch_bounds__(256) void k_adj(const unsigned short* __restrict__ mu, float* __restrict__ adj){
    int t  = threadIdx.x;
    int l  = t & 63;
    int w  = t >> 6;
    int wr = w >> 1, wc = w & 1;
    int Ibase = blockIdx.y*128 + wr*64;
    int Jbase = blockIdx.x*128 + wc*64;
    int lr = l & 15;
    int kg = l >> 4;

    bf16x8 afr[4][2], bfr[4][2];
    #pragma unroll
    for (int mt=0; mt<4; mt++){
        const unsigned short* p = mu + (size_t)(Ibase + mt*16 + lr)*HID2 + kg*8;
        afr[mt][0] = *(const bf16x8*)(p);
        afr[mt][1] = *(const bf16x8*)(p + 32);
    }
    #pragma unroll
    for (int nt=0; nt<4; nt++){
        const unsigned short* p = mu + (size_t)(Jbase + nt*16 + lr)*HID2 + kg*8;
        bfr[nt][0] = *(const bf16x8*)(p);
        bfr[nt][1] = *(const bf16x8*)(p + 32);
    }

    f32x4 acc[4][4];
    #pragma unroll
    for (int mt=0; mt<4; mt++)
        #pragma unroll
        for (int nt=0; nt<4; nt++)
            acc[mt][nt] = (f32x4){0.f,0.f,0.f,0.f};

    #pragma unroll
    for (int kc=0; kc<2; kc++)
        #pragma unroll
        for (int mt=0; mt<4; mt++)
            #pragma unroll
            for (int nt=0; nt<4; nt++)
                acc[mt][nt] = __builtin_amdgcn_mfma_f32_16x16x32_bf16(afr[mt][kc], bfr[nt][kc], acc[mt][nt], 0, 0, 0);

    __shared__ float wt[4][16][68];
    float* myt = &wt[w][0][0];
    #pragma unroll
    for (int mt=0; mt<4; mt++){
        asm volatile("s_waitcnt lgkmcnt(0)" ::: "memory");
        #pragma unroll
        for (int nt=0; nt<4; nt++)
            #pragma unroll
            for (int r=0; r<4; r++)
                myt[(kg*4+r)*68 + nt*16 + lr] = acc[mt][nt][r];
        asm volatile("s_waitcnt lgkmcnt(0)" ::: "memory");
        __builtin_amdgcn_sched_barrier(0);
        #pragma unroll
        for (int p=0; p<4; p++){
            int row = p*4 + (l >> 4);          // 0..15
            int col = (l & 15)*4;              // 0..60
            f32x4 v = *(const f32x4*)&myt[row*68 + col];
            f32x4 o;
            #pragma unroll
            for (int j=0;j<4;j++)
                o[j] = __builtin_amdgcn_rcpf(1.f + __expf(-v[j]));
            __builtin_nontemporal_store(o, (f32x4*)(adj + (size_t)(Ibase + mt*16 + row)*N_NODES + Jbase + col));
        }
    }
}

// ---------------- launch ----------------

extern "C" void kernel_launch(void* const* d_in, const int* in_sizes, int n_in,
                              void* d_out, int out_size, void* d_ws, size_t ws_size,
                              hipStream_t stream){
    const float* x   = (const float*)d_in[0];
    const int*   ei  = (const int*)  d_in[1];
    const float* W1  = (const float*)d_in[2];
    const float* b1  = (const float*)d_in[3];
    const float* W2  = (const float*)d_in[4];
    const float* b2  = (const float*)d_in[5];
    const float* Wmu = (const float*)d_in[6];
    const float* bmu = (const float*)d_in[7];
    const float* Wlv = (const float*)d_in[8];
    const float* blv = (const float*)d_in[9];

    char* ws = (char*)d_ws;
    int*   fillc  = (int*)  (ws + 0);        // 32 KB (zeroed by k_pre)
    unsigned short* WcT = (unsigned short*)(ws + 32768);   // 64 KB -> 98304
    float* cvec   = (float*)(ws + 98304);    // 512 B -> 98816
    unsigned short* muBf = (unsigned short*)(ws + 98816);  // 1 MB -> 1,147,392

    float* adj   = (float*)d_out;
    float* outMu = adj + (size_t)N_NODES*N_NODES;
    float* outLv = outMu + (size_t)N_NODES*HID2;

    // dead adj region reused as scratch (overwritten by k_adj at the end):
    unsigned short* Ubf   = (unsigned short*)adj;                          // [0, 2MB)
    unsigned short* Tbf   = (unsigned short*)((char*)adj + 16*1024*1024);  // [16MB, 18MB)
    unsigned short* slots = (unsigned short*)((char*)adj + 32*1024*1024);  // [32MB, +3MB)

    k_pre      <<<136, 256, 0, stream>>>(W1, W2, Wmu, Wlv, b1, b2, WcT, cvec, (float*)ws);
    k_fill_gemm<<<FILL_BLK + 256, 256, 0, stream>>>(ei, fillc, slots, x, WcT, Ubf);
    k_spmm     <<<N_NODES/4, 256, 0, stream>>>(Ubf, slots, fillc, cvec, Tbf);
    k_spmm_out <<<N_NODES/4, 256, 0, stream>>>(Tbf, slots, fillc, bmu, blv,
                                               outMu, outLv, muBf);
    k_adj      <<<dim3(N_NODES/128, N_NODES/128), 256, 0, stream>>>(muBf, adj);
}